// Round 13
// baseline (138.298 us; speedup 1.0000x reference)
//
#include <hip/hip_runtime.h>
#include <hip/hip_bf16.h>

// QuantumFeedForward, fully fused:
//   q[n,w] = prod_{v in M_w} cos(theta_v)*cos(x[n,v])   (analytic circuit collapse)
//   out    = relu(q@W1^T+b1) @ W2^T + b2
// 32x32x16 MFMA. H^T = mfma(W1aug-frag, qaug-frag) -> pk-relu -> cvt_pk ->
// v_permlane32_swap -> GEMM A-quads in registers (dataflow verified R9-R12).
// R13: 1-kt SOFTWARE PIPELINE to break the per-wave serial chain
// (HGENmfma -> VALUpost -> GEMMmfma). During kt's GEMM we run HGEN for kt+1:
// HGEN-mfma(kt+1) issues first, GEMM(kt) j=0 mfmas cover its latency on the
// matrix pipe, HGEN-post(kt+1) on VALU overlaps GEMM j=1. aq/wf double-banked
// with STATIC names (aqA/aqB, wfX/wfY); last pair peeled -> compile-time guards.
// W2 B-frags LDS-staged in fragment order (linear = gload_lds-legal and
// conflict-free ds_read); one vmcnt(0)+s_barrier per 128-k pair (16 total).

typedef __attribute__((ext_vector_type(8))) short bf16x8;
typedef __attribute__((ext_vector_type(16))) float f32x16;
typedef __attribute__((ext_vector_type(8))) unsigned short us8;
typedef unsigned int u32;

#define NTOK  16384
#define EMBED 512
#define FFN   2048
#define NQ    10
#define BM    128
#define BN    128
#define NPAIR 16          // K-pairs of 128 k (2 kt of 64)

__device__ __forceinline__ unsigned short f2bf(float f) {
  union { float f; unsigned int u; } a; a.f = f;
  unsigned int r = a.u + 0x7FFFu + ((a.u >> 16) & 1u);   // RNE
  return (unsigned short)(r >> 16);
}

__device__ __forceinline__ void gload_lds16(const void* g, void* l) {
  __builtin_amdgcn_global_load_lds(
      (const __attribute__((address_space(1))) unsigned int*)g,
      (__attribute__((address_space(3))) unsigned int*)l, 16, 0, 0);
}

// ---------------- K0: fused prep (W2f + Qf + W1f), one launch ----------------
// W2f[((tile*128+kb)*64+l)*8+e] = W2[col=tile*32+(l&31)][k=kb*16+(l>>5)*8+e]
// Qf [(tile*64+l)*8+e]          = qaug[wire=(l>>5)*8+e][token=tile*32+(l&31)]
// W1f[(blk*64+l)*8+e]           = W1aug[wire=(l>>5)*8+e][k=blk*32+(l&31)]
__global__ __launch_bounds__(256) void k_prep(const float* __restrict__ x,
                                              const float* __restrict__ theta,
                                              const float* __restrict__ W1,
                                              const float* __restrict__ b1,
                                              const float* __restrict__ W2,
                                              unsigned short* __restrict__ W2f,
                                              unsigned short* __restrict__ W1f,
                                              unsigned short* __restrict__ Qf) {
  int bb = blockIdx.x;
  if (bb < 512) {                       // ---- W2f: 131072 chunks ----
    int gid = bb * 256 + threadIdx.x;
    int l = gid & 63, kb = (gid >> 6) & 127, tile = gid >> 13;
    int col = tile * 32 + (l & 31);
    int k0 = kb * 16 + (l >> 5) * 8;
    const float* src = W2 + (size_t)col * FFN + k0;
    float4 v0 = *(const float4*)src;
    float4 v1 = *(const float4*)(src + 4);
    us8 o;
    o[0] = f2bf(v0.x); o[1] = f2bf(v0.y); o[2] = f2bf(v0.z); o[3] = f2bf(v0.w);
    o[4] = f2bf(v1.x); o[5] = f2bf(v1.y); o[6] = f2bf(v1.z); o[7] = f2bf(v1.w);
    *(us8*)(W2f + (size_t)gid * 8) = o;
  } else if (bb < 640) {                // ---- Qf: 32768 chunks ----
    int gid = (bb - 512) * 256 + threadIdx.x;
    int l = gid & 63, tile = gid >> 6;
    int tok = tile * 32 + (l & 31), g = l >> 5;
    const int masks[NQ] = {0x2AB,0x3FD,0x3FA,0x3F5,0x3EA,0x3D5,0x3AA,0x355,0x2AA,0x155};
    float z[NQ], qv[NQ];
#pragma unroll
    for (int w = 0; w < NQ; ++w)
      z[w] = __builtin_cosf(x[(size_t)tok * EMBED + w]) * __builtin_cosf(theta[w]);
#pragma unroll
    for (int w = 0; w < NQ; ++w) {
      float p = 1.f;
#pragma unroll
      for (int v = 0; v < NQ; ++v)
        if ((masks[w] >> v) & 1) p *= z[v];
      qv[w] = p;
    }
    us8 o = (us8)0;
    if (g == 0) {
#pragma unroll
      for (int e = 0; e < 8; ++e) o[e] = f2bf(qv[e]);
    } else {
      o[0] = f2bf(qv[8]); o[1] = f2bf(qv[9]); o[2] = f2bf(1.f);
    }
    *(us8*)(Qf + (size_t)gid * 8) = o;
  } else {                              // ---- W1f: 4096 chunks ----
    int gid = (bb - 640) * 256 + threadIdx.x;
    int l = gid & 63, blk = gid >> 6;
    int k = blk * 32 + (l & 31);
    int wg = (l >> 5) * 8;
    us8 o;
#pragma unroll
    for (int e = 0; e < 8; ++e) {
      int wire = wg + e;
      float v = (wire < NQ) ? W1[k * NQ + wire] : (wire == NQ ? b1[k] : 0.f);
      o[e] = f2bf(v);
    }
    *(us8*)(W1f + (size_t)gid * 8) = o;
  }
}

// ---------------- K1: fused H-gen + GEMM, pipelined ----------------
__global__ __launch_bounds__(512, 4) void k_fused(const unsigned short* __restrict__ Qf,
                                                  const unsigned short* __restrict__ W1f,
                                                  const unsigned short* __restrict__ W2f,
                                                  const float* __restrict__ b2,
                                                  float* __restrict__ out) {
  __shared__ short Bw[2][32 * 64 * 8];   // 2 x 32KB: [tile2*8+kbl][lane][8], frag order

  // XCD-aware bijective swizzle: 512 blocks, 64 consecutive per XCD; n fastest.
  int bid = blockIdx.x;
  int swz = (bid & 7) * 64 + (bid >> 3);
  const int m0 = (swz >> 2) * BM;
  const int n0 = (swz & 3) * BN;
  const int tid  = threadIdx.x;
  const int lane = tid & 63;
  const int wave = tid >> 6;           // 8 waves: 4 (M) x 2 (N), 32x64 tiles
  const int wm = wave >> 1, wn = wave & 1;
  const int h = lane >> 5, t31 = lane & 31;
  const int nt0 = n0 >> 5;             // global col-tile base (4 tiles of 32)

  // q_aug B-frag for this wave's 32 tokens (single load, register-resident)
  bf16x8 qf = *(const bf16x8*)&Qf[(((size_t)(m0 >> 5) + wm) * 64 + lane) * 8];

  f32x16 acc[2] = {};
  bf16x8 wfX0, wfX1, wfY0, wfY1;                 // W1 frags, double-banked
  bf16x8 aqA00, aqA01, aqA10, aqA11;             // A-quads, even-kt bank
  bf16x8 aqB00, aqB01, aqB10, aqB11;             // A-quads, odd-kt bank

  // Stage one 128-k pair: 2048 Bw chunks (4/thread).
#define STAGE(P, B)                                                             \
  { _Pragma("unroll")                                                           \
    for (int hf = 0; hf < 4; ++hf) {                                            \
      int ch = hf * 512 + tid;                                                  \
      int tile2 = ch >> 9, kbl = (ch >> 6) & 7, ln = ch & 63;                   \
      gload_lds16(&W2f[(((size_t)(nt0 + tile2) * 128 + (P) * 8 + kbl) * 64 + ln) * 8], \
                  &Bw[B][ch * 8]);                                              \
    } }

#define WLOAD2(R0, R1, KT)                                                      \
  { R0 = *(const bf16x8*)&W1f[(((size_t)(KT) * 2 + 0) * 64 + lane) * 8];        \
    R1 = *(const bf16x8*)&W1f[(((size_t)(KT) * 2 + 1) * 64 + lane) * 8]; }

#define HGEN_MFMA(D, WF)                                                        \
  { f32x16 zz = {};                                                             \
    D = __builtin_amdgcn_mfma_f32_32x32x16_bf16((WF), qf, zz, 0, 0, 0); }

#define HGEN_POST(D, AQ0, AQ1)                                                  \
  { f32x16 zz2 = {};                                                            \
    D = __builtin_elementwise_max(D, zz2);                                      \
    u32 dw0, dw1, dw2, dw3, dw4, dw5, dw6, dw7;                                 \
    asm("v_cvt_pk_bf16_f32 %0, %1, %2":"=v"(dw0):"v"(D[0]),"v"(D[1]));          \
    asm("v_cvt_pk_bf16_f32 %0, %1, %2":"=v"(dw1):"v"(D[2]),"v"(D[3]));          \
    asm("v_cvt_pk_bf16_f32 %0, %1, %2":"=v"(dw2):"v"(D[4]),"v"(D[5]));          \
    asm("v_cvt_pk_bf16_f32 %0, %1, %2":"=v"(dw3):"v"(D[6]),"v"(D[7]));          \
    asm("v_cvt_pk_bf16_f32 %0, %1, %2":"=v"(dw4):"v"(D[8]),"v"(D[9]));          \
    asm("v_cvt_pk_bf16_f32 %0, %1, %2":"=v"(dw5):"v"(D[10]),"v"(D[11]));        \
    asm("v_cvt_pk_bf16_f32 %0, %1, %2":"=v"(dw6):"v"(D[12]),"v"(D[13]));        \
    asm("v_cvt_pk_bf16_f32 %0, %1, %2":"=v"(dw7):"v"(D[14]),"v"(D[15]));        \
    asm("v_permlane32_swap_b32 %0, %1" : "+v"(dw0), "+v"(dw2));                 \
    asm("v_permlane32_swap_b32 %0, %1" : "+v"(dw1), "+v"(dw3));                 \
    asm("v_permlane32_swap_b32 %0, %1" : "+v"(dw4), "+v"(dw6));                 \
    asm("v_permlane32_swap_b32 %0, %1" : "+v"(dw5), "+v"(dw7));                 \
    union { u32 u[4]; bf16x8 v; } u0, u1;                                       \
    u0.u[0]=dw0; u0.u[1]=dw1; u0.u[2]=dw2; u0.u[3]=dw3;                         \
    u1.u[0]=dw4; u1.u[1]=dw5; u1.u[2]=dw6; u1.u[3]=dw7;                         \
    AQ0 = u0.v; AQ1 = u1.v; }

#define GEMMJ(J, Q, B, A00, A01, A10, A11)                                      \
  { bf16x8 bg0 = *(const bf16x8*)&Bw[B][(((wn * 2 + (J)) * 8 + (Q) * 4 + 0) * 64 + lane) * 8]; \
    bf16x8 bg1 = *(const bf16x8*)&Bw[B][(((wn * 2 + (J)) * 8 + (Q) * 4 + 1) * 64 + lane) * 8]; \
    bf16x8 bg2 = *(const bf16x8*)&Bw[B][(((wn * 2 + (J)) * 8 + (Q) * 4 + 2) * 64 + lane) * 8]; \
    bf16x8 bg3 = *(const bf16x8*)&Bw[B][(((wn * 2 + (J)) * 8 + (Q) * 4 + 3) * 64 + lane) * 8]; \
    __builtin_amdgcn_s_setprio(1);                                              \
    acc[J] = __builtin_amdgcn_mfma_f32_32x32x16_bf16(A00, bg0, acc[J], 0, 0, 0); \
    acc[J] = __builtin_amdgcn_mfma_f32_32x32x16_bf16(A01, bg1, acc[J], 0, 0, 0); \
    acc[J] = __builtin_amdgcn_mfma_f32_32x32x16_bf16(A10, bg2, acc[J], 0, 0, 0); \
    acc[J] = __builtin_amdgcn_mfma_f32_32x32x16_bf16(A11, bg3, acc[J], 0, 0, 0); \
    __builtin_amdgcn_s_setprio(0); }

  // kt = 2P (even): GEMM on aqA, pipeline HGEN(kt+1) from wfX into aqB.
#define KT_EVEN(P, B, MORE)                                                     \
  { if (MORE) WLOAD2(wfY0, wfY1, 2 * (P) + 2);                                  \
    f32x16 d0;                                                                  \
    HGEN_MFMA(d0, wfX0);                                                        \
    GEMMJ(0, 0, B, aqA00, aqA01, aqA10, aqA11);                                 \
    HGEN_POST(d0, aqB00, aqB01);                                                \
    f32x16 d1;                                                                  \
    HGEN_MFMA(d1, wfX1);                                                        \
    GEMMJ(1, 0, B, aqA00, aqA01, aqA10, aqA11);                                 \
    HGEN_POST(d1, aqB10, aqB11); }

  // kt = 2P+1 (odd): GEMM on aqB, pipeline HGEN(kt+1 = next pair) from wfY into aqA.
#define KT_ODD(P, B, MORE)                                                      \
  { if (MORE) WLOAD2(wfX0, wfX1, 2 * (P) + 3);                                  \
    f32x16 d0;                                                                  \
    if (MORE) { HGEN_MFMA(d0, wfY0); }                                          \
    GEMMJ(0, 1, B, aqB00, aqB01, aqB10, aqB11);                                 \
    if (MORE) { HGEN_POST(d0, aqA00, aqA01); }                                  \
    f32x16 d1;                                                                  \
    if (MORE) { HGEN_MFMA(d1, wfY1); }                                          \
    GEMMJ(1, 1, B, aqB00, aqB01, aqB10, aqB11);                                 \
    if (MORE) { HGEN_POST(d1, aqA10, aqA11); } }

#define PAIR(P, B, MORE)                                                        \
  { asm volatile("s_waitcnt vmcnt(0)" ::: "memory");   /* stage(P) landed */    \
    __builtin_amdgcn_s_barrier();                      /* buf B^1 reads done */ \
    asm volatile("" ::: "memory");                                              \
    if (MORE) STAGE((P) + 1, (B) ^ 1);                                          \
    KT_EVEN(P, B, MORE);                                                        \
    KT_ODD(P, B, MORE); }

  // ---- prologue: wf(kt0) temp + wf(kt1) -> wfX; stage pair 0; aq(kt0) -> aqA ----
  {
    bf16x8 wfP0, wfP1;
    WLOAD2(wfP0, wfP1, 0);
    WLOAD2(wfX0, wfX1, 1);
    STAGE(0, 0);
    f32x16 d0;
    HGEN_MFMA(d0, wfP0);
    HGEN_POST(d0, aqA00, aqA01);
    f32x16 d1;
    HGEN_MFMA(d1, wfP1);
    HGEN_POST(d1, aqA10, aqA11);
  }

  // ---- main loop: two pairs per iteration (static parity); last pair peeled ----
  for (int p2 = 0; p2 < 7; ++p2) {
    PAIR(2 * p2,     0, 1);
    PAIR(2 * p2 + 1, 1, 1);
  }
  PAIR(14, 0, 1);
  PAIR(15, 1, 0);

  // ---- epilogue: out = acc + b2 ----
#pragma unroll
  for (int j = 0; j < 2; ++j) {
    const int col = n0 + wn * 64 + j * 32 + t31;
    const float bbv = b2[col];
#pragma unroll
    for (int r = 0; r < 16; ++r) {
      int tok = m0 + wm * 32 + (r & 3) + 8 * (r >> 2) + 4 * h;
      out[(size_t)tok * EMBED + col] = acc[j][r] + bbv;
    }
  }
#undef STAGE
#undef WLOAD2
#undef HGEN_MFMA
#undef HGEN_POST
#undef GEMMJ
#undef KT_EVEN
#undef KT_ODD
#undef PAIR
}

extern "C" void kernel_launch(void* const* d_in, const int* in_sizes, int n_in,
                              void* d_out, int out_size, void* d_ws, size_t ws_size,
                              hipStream_t stream) {
  const float* x     = (const float*)d_in[0];
  const float* theta = (const float*)d_in[1];
  const float* W1    = (const float*)d_in[2];
  const float* b1    = (const float*)d_in[3];
  const float* W2    = (const float*)d_in[4];
  const float* b2    = (const float*)d_in[5];
  float* out = (float*)d_out;

  char* ws = (char*)d_ws;
  unsigned short* W2f = (unsigned short*)ws;                          // 2 MB
  unsigned short* W1f = (unsigned short*)(ws + (2u << 20));           // 64 KB
  unsigned short* Qfg = (unsigned short*)(ws + (2u << 20) + (64u << 10)); // 512 KB

  k_prep <<<656, 256, 0, stream>>>(x, theta, W1, b1, W2, W2f, W1f, Qfg);
  k_fused<<<(NTOK / BM) * (EMBED / BN), 512, 0, stream>>>(Qfg, W1f, W2f, b2, out);
}

// Round 14
// 55.671 us; speedup vs baseline: 2.4842x; 2.4842x over previous
//
#include <hip/hip_runtime.h>
#include <hip/hip_bf16.h>

// QuantumFeedForward, fully fused:
//   q[n,w] = prod_{v in M_w} cos(theta_v)*cos(x[n,v])   (analytic circuit collapse)
//   out    = relu(q@W1^T+b1) @ W2^T + b2
// 32x32x16 MFMA. H^T = mfma(W1aug-frag, qaug-frag) -> pk-relu -> cvt_pk ->
// v_permlane32_swap -> GEMM A-quads in registers (dataflow verified R9-R12).
// R14: small sync domains. 256-thread blocks (4 waves, 32x64 wave tiles),
// BM=128 x BN=64, grid 1024 = 4 independent blocks/CU (4 barrier groups vs 2).
// s_setprio REMOVED (m190: hurts lockstep GEMM). GEMM j-chains interleaved.
// W2 B-frags LDS-staged in fragment order (linear = gload_lds-legal and
// conflict-free ds_read); one vmcnt(0)+s_barrier per 64-k tile.

typedef __attribute__((ext_vector_type(8))) short bf16x8;
typedef __attribute__((ext_vector_type(16))) float f32x16;
typedef __attribute__((ext_vector_type(8))) unsigned short us8;
typedef unsigned int u32;

#define NTOK  16384
#define EMBED 512
#define FFN   2048
#define NQ    10
#define BM    128
#define BN    64
#define NKT   32          // K-tiles of 64 k

__device__ __forceinline__ unsigned short f2bf(float f) {
  union { float f; unsigned int u; } a; a.f = f;
  unsigned int r = a.u + 0x7FFFu + ((a.u >> 16) & 1u);   // RNE
  return (unsigned short)(r >> 16);
}

__device__ __forceinline__ void gload_lds16(const void* g, void* l) {
  __builtin_amdgcn_global_load_lds(
      (const __attribute__((address_space(1))) unsigned int*)g,
      (__attribute__((address_space(3))) unsigned int*)l, 16, 0, 0);
}

// ---------------- K0: fused prep (W2f + Qf + W1f), one launch ----------------
// W2f[((tile*128+kb)*64+l)*8+e] = W2[col=tile*32+(l&31)][k=kb*16+(l>>5)*8+e]
// Qf [(tile*64+l)*8+e]          = qaug[wire=(l>>5)*8+e][token=tile*32+(l&31)]
// W1f[(blk*64+l)*8+e]           = W1aug[wire=(l>>5)*8+e][k=blk*32+(l&31)]
__global__ __launch_bounds__(256) void k_prep(const float* __restrict__ x,
                                              const float* __restrict__ theta,
                                              const float* __restrict__ W1,
                                              const float* __restrict__ b1,
                                              const float* __restrict__ W2,
                                              unsigned short* __restrict__ W2f,
                                              unsigned short* __restrict__ W1f,
                                              unsigned short* __restrict__ Qf) {
  int bb = blockIdx.x;
  if (bb < 512) {                       // ---- W2f: 131072 chunks ----
    int gid = bb * 256 + threadIdx.x;
    int l = gid & 63, kb = (gid >> 6) & 127, tile = gid >> 13;
    int col = tile * 32 + (l & 31);
    int k0 = kb * 16 + (l >> 5) * 8;
    const float* src = W2 + (size_t)col * FFN + k0;
    float4 v0 = *(const float4*)src;
    float4 v1 = *(const float4*)(src + 4);
    us8 o;
    o[0] = f2bf(v0.x); o[1] = f2bf(v0.y); o[2] = f2bf(v0.z); o[3] = f2bf(v0.w);
    o[4] = f2bf(v1.x); o[5] = f2bf(v1.y); o[6] = f2bf(v1.z); o[7] = f2bf(v1.w);
    *(us8*)(W2f + (size_t)gid * 8) = o;
  } else if (bb < 640) {                // ---- Qf: 32768 chunks ----
    int gid = (bb - 512) * 256 + threadIdx.x;
    int l = gid & 63, tile = gid >> 6;
    int tok = tile * 32 + (l & 31), g = l >> 5;
    const int masks[NQ] = {0x2AB,0x3FD,0x3FA,0x3F5,0x3EA,0x3D5,0x3AA,0x355,0x2AA,0x155};
    float z[NQ], qv[NQ];
#pragma unroll
    for (int w = 0; w < NQ; ++w)
      z[w] = __builtin_cosf(x[(size_t)tok * EMBED + w]) * __builtin_cosf(theta[w]);
#pragma unroll
    for (int w = 0; w < NQ; ++w) {
      float p = 1.f;
#pragma unroll
      for (int v = 0; v < NQ; ++v)
        if ((masks[w] >> v) & 1) p *= z[v];
      qv[w] = p;
    }
    us8 o = (us8)0;
    if (g == 0) {
#pragma unroll
      for (int e = 0; e < 8; ++e) o[e] = f2bf(qv[e]);
    } else {
      o[0] = f2bf(qv[8]); o[1] = f2bf(qv[9]); o[2] = f2bf(1.f);
    }
    *(us8*)(Qf + (size_t)gid * 8) = o;
  } else {                              // ---- W1f: 4096 chunks ----
    int gid = (bb - 640) * 256 + threadIdx.x;
    int l = gid & 63, blk = gid >> 6;
    int k = blk * 32 + (l & 31);
    int wg = (l >> 5) * 8;
    us8 o;
#pragma unroll
    for (int e = 0; e < 8; ++e) {
      int wire = wg + e;
      float v = (wire < NQ) ? W1[k * NQ + wire] : (wire == NQ ? b1[k] : 0.f);
      o[e] = f2bf(v);
    }
    *(us8*)(W1f + (size_t)gid * 8) = o;
  }
}

// ---------------- K1: fused H-gen + GEMM, 4 blocks/CU ----------------
__global__ __launch_bounds__(256, 4) void k_fused(const unsigned short* __restrict__ Qf,
                                                  const unsigned short* __restrict__ W1f,
                                                  const unsigned short* __restrict__ W2f,
                                                  const float* __restrict__ b2,
                                                  float* __restrict__ out) {
  __shared__ short Bw[2][8 * 64 * 8];    // 2 x 8KB: [tile2*4+kb][lane][8], frag order
  __shared__ short W1s[2][2 * 64 * 8];   // 2 x 2KB: [b][lane][8]

  // XCD-aware bijective swizzle: 1024 blocks, 128 consecutive per XCD; n fastest.
  int bid = blockIdx.x;
  int swz = (bid & 7) * 128 + (bid >> 3);
  const int m0 = (swz >> 3) * BM;      // 128 m-tiles
  const int n0 = (swz & 7) * BN;       // 8 n-tiles
  const int tid  = threadIdx.x;
  const int lane = tid & 63;
  const int wave = tid >> 6;           // 4 waves, each 32 tok x 64 cols
  const int h = lane >> 5, t31 = lane & 31;
  const int nt0 = n0 >> 5;             // global col-tile base (2 tiles of 32)

  // q_aug B-frag for this wave's 32 tokens (single load, register-resident)
  bf16x8 qf = *(const bf16x8*)&Qf[(((size_t)(m0 >> 5) + wave) * 64 + lane) * 8];

  f32x16 acc[2] = {};

  // Stage one 64-k tile: 512 Bw chunks (2/thread) + 128 W1 chunks.
#define STAGE(KT, B)                                                            \
  { _Pragma("unroll")                                                           \
    for (int hf = 0; hf < 2; ++hf) {                                            \
      int ch = hf * 256 + tid;                                                  \
      int tile2 = ch >> 8, kb = (ch >> 6) & 3, ln = ch & 63;                    \
      gload_lds16(&W2f[(((size_t)(nt0 + tile2) * 128 + (KT) * 4 + kb) * 64 + ln) * 8], \
                  &Bw[B][ch * 8]);                                              \
    }                                                                           \
    if (tid < 128)                                                              \
      gload_lds16(&W1f[(((size_t)(KT) * 2 + (tid >> 6)) * 64 + (tid & 63)) * 8],\
                  &W1s[B][tid * 8]); }

  // H^T = mfma(W1aug, qaug); pk-relu; cvt_pk; permlane32_swap -> A-quads
#define HGEN1(WF, AQ0, AQ1)                                                     \
  { f32x16 zz = {};                                                             \
    f32x16 d = __builtin_amdgcn_mfma_f32_32x32x16_bf16((WF), qf, zz, 0, 0, 0);  \
    d = __builtin_elementwise_max(d, zz);                                       \
    u32 dw0, dw1, dw2, dw3, dw4, dw5, dw6, dw7;                                 \
    asm("v_cvt_pk_bf16_f32 %0, %1, %2":"=v"(dw0):"v"(d[0]),"v"(d[1]));          \
    asm("v_cvt_pk_bf16_f32 %0, %1, %2":"=v"(dw1):"v"(d[2]),"v"(d[3]));          \
    asm("v_cvt_pk_bf16_f32 %0, %1, %2":"=v"(dw2):"v"(d[4]),"v"(d[5]));          \
    asm("v_cvt_pk_bf16_f32 %0, %1, %2":"=v"(dw3):"v"(d[6]),"v"(d[7]));          \
    asm("v_cvt_pk_bf16_f32 %0, %1, %2":"=v"(dw4):"v"(d[8]),"v"(d[9]));          \
    asm("v_cvt_pk_bf16_f32 %0, %1, %2":"=v"(dw5):"v"(d[10]),"v"(d[11]));        \
    asm("v_cvt_pk_bf16_f32 %0, %1, %2":"=v"(dw6):"v"(d[12]),"v"(d[13]));        \
    asm("v_cvt_pk_bf16_f32 %0, %1, %2":"=v"(dw7):"v"(d[14]),"v"(d[15]));        \
    asm("v_permlane32_swap_b32 %0, %1" : "+v"(dw0), "+v"(dw2));                 \
    asm("v_permlane32_swap_b32 %0, %1" : "+v"(dw1), "+v"(dw3));                 \
    asm("v_permlane32_swap_b32 %0, %1" : "+v"(dw4), "+v"(dw6));                 \
    asm("v_permlane32_swap_b32 %0, %1" : "+v"(dw5), "+v"(dw7));                 \
    union { u32 u[4]; bf16x8 v; } u0, u1;                                       \
    u0.u[0]=dw0; u0.u[1]=dw1; u0.u[2]=dw2; u0.u[3]=dw3;                         \
    u1.u[0]=dw4; u1.u[1]=dw5; u1.u[2]=dw6; u1.u[3]=dw7;                         \
    AQ0 = u0.v; AQ1 = u1.v; }

  // ---- prologue: stage tile 0 ----
  STAGE(0, 0);

  // ---- main loop: one 64-k tile per iteration ----
  for (int kt = 0; kt < NKT; ++kt) {
    const int cur = kt & 1;
    asm volatile("s_waitcnt vmcnt(0)" ::: "memory");   // stage(kt) landed
    __builtin_amdgcn_s_barrier();                      // 4-wave group: buf cur^1 free
    asm volatile("" ::: "memory");
    if (kt + 1 < NKT) STAGE(kt + 1, cur ^ 1);          // post-barrier: race-safe

    // W1 frags + HGEN -> A-quads (aq[s], s = kb-local 0..3)
    bf16x8 wf0 = *(const bf16x8*)&W1s[cur][(0 * 64 + lane) * 8];
    bf16x8 wf1 = *(const bf16x8*)&W1s[cur][(1 * 64 + lane) * 8];
    bf16x8 aq0, aq1, aq2, aq3;
    HGEN1(wf0, aq0, aq1);
    HGEN1(wf1, aq2, aq3);

    // GEMM: 8 mfma, j-chains interleaved (acc[0]/acc[1] alternate at issue)
    bf16x8 bg00 = *(const bf16x8*)&Bw[cur][((0 * 4 + 0) * 64 + lane) * 8];
    bf16x8 bg01 = *(const bf16x8*)&Bw[cur][((0 * 4 + 1) * 64 + lane) * 8];
    bf16x8 bg02 = *(const bf16x8*)&Bw[cur][((0 * 4 + 2) * 64 + lane) * 8];
    bf16x8 bg03 = *(const bf16x8*)&Bw[cur][((0 * 4 + 3) * 64 + lane) * 8];
    bf16x8 bg10 = *(const bf16x8*)&Bw[cur][((1 * 4 + 0) * 64 + lane) * 8];
    bf16x8 bg11 = *(const bf16x8*)&Bw[cur][((1 * 4 + 1) * 64 + lane) * 8];
    bf16x8 bg12 = *(const bf16x8*)&Bw[cur][((1 * 4 + 2) * 64 + lane) * 8];
    bf16x8 bg13 = *(const bf16x8*)&Bw[cur][((1 * 4 + 3) * 64 + lane) * 8];
    acc[0] = __builtin_amdgcn_mfma_f32_32x32x16_bf16(aq0, bg00, acc[0], 0, 0, 0);
    acc[1] = __builtin_amdgcn_mfma_f32_32x32x16_bf16(aq0, bg10, acc[1], 0, 0, 0);
    acc[0] = __builtin_amdgcn_mfma_f32_32x32x16_bf16(aq1, bg01, acc[0], 0, 0, 0);
    acc[1] = __builtin_amdgcn_mfma_f32_32x32x16_bf16(aq1, bg11, acc[1], 0, 0, 0);
    acc[0] = __builtin_amdgcn_mfma_f32_32x32x16_bf16(aq2, bg02, acc[0], 0, 0, 0);
    acc[1] = __builtin_amdgcn_mfma_f32_32x32x16_bf16(aq2, bg12, acc[1], 0, 0, 0);
    acc[0] = __builtin_amdgcn_mfma_f32_32x32x16_bf16(aq3, bg03, acc[0], 0, 0, 0);
    acc[1] = __builtin_amdgcn_mfma_f32_32x32x16_bf16(aq3, bg13, acc[1], 0, 0, 0);
  }

  // ---- epilogue: out = acc + b2 ----
#pragma unroll
  for (int j = 0; j < 2; ++j) {
    const int col = n0 + j * 32 + t31;
    const float bbv = b2[col];
#pragma unroll
    for (int r = 0; r < 16; ++r) {
      int tok = m0 + wave * 32 + (r & 3) + 8 * (r >> 2) + 4 * h;
      out[(size_t)tok * EMBED + col] = acc[j][r] + bbv;
    }
  }
#undef STAGE
#undef HGEN1
}

extern "C" void kernel_launch(void* const* d_in, const int* in_sizes, int n_in,
                              void* d_out, int out_size, void* d_ws, size_t ws_size,
                              hipStream_t stream) {
  const float* x     = (const float*)d_in[0];
  const float* theta = (const float*)d_in[1];
  const float* W1    = (const float*)d_in[2];
  const float* b1    = (const float*)d_in[3];
  const float* W2    = (const float*)d_in[4];
  const float* b2    = (const float*)d_in[5];
  float* out = (float*)d_out;

  char* ws = (char*)d_ws;
  unsigned short* W2f = (unsigned short*)ws;                          // 2 MB
  unsigned short* W1f = (unsigned short*)(ws + (2u << 20));           // 64 KB
  unsigned short* Qfg = (unsigned short*)(ws + (2u << 20) + (64u << 10)); // 512 KB

  k_prep <<<656, 256, 0, stream>>>(x, theta, W1, b1, W2, W2f, W1f, Qfg);
  k_fused<<<(NTOK / BM) * (EMBED / BN), 256, 0, stream>>>(Qfg, W1f, W2f, b2, out);
}